// Round 1
// baseline (61.068 us; speedup 1.0000x reference)
//
#include <hip/hip_runtime.h>

typedef unsigned int uint;

// Problem constants (from setup_inputs)
#define B_     2
#define C_     16
#define H_     66
#define W_     66
#define O_     64
#define CKK    144
#define NCH    36          // CKK/4
#define DIM    64          // output spatial
#define L_     4096        // DIM*DIM
#define N_     8192        // B_*L_
#define PLANE  524288      // N_*O_  (stride between (c,s) planes of rand_idx)
#define NTILES 512         // N_/16
#define TROWS  53          // table rows 8..60
#define TCOLS  1000

// ---------------- Kernel A: quantize x and pack 4 channels/byte-chunk -------
__global__ void k_quant(const float* __restrict__ x,
                        const float* __restrict__ pmin,
                        const float* __restrict__ pmax,
                        uint* __restrict__ xq) {
    int gid = blockIdx.x * 256 + threadIdx.x;   // gid = n*36 + c, exact grid
    int n = gid / NCH;
    int c = gid - n * NCH;
    int b = n >> 12, l = n & (L_ - 1);
    int h = l >> 6, w = l & (DIM - 1);
    float mn = pmin[0];
    float sc = pmax[0] - mn;
    uint packed = 0;
#pragma unroll
    for (int k = 0; k < 4; ++k) {
        int j  = c * 4 + k;
        int ci = j / 9;
        int r  = j - ci * 9;
        int kh = r / 3;
        int kw = r - kh * 3;
        float v = x[((b * C_ + ci) * H_ + (h + kh)) * W_ + (w + kw)];
        float t = (v - mn) / sc * 15.0f;              // match jax f32 op order
        float q = fminf(fmaxf(rintf(t), 0.0f), 15.0f); // rintf = round-half-even
        packed |= ((uint)q) << (8 * k);
    }
    xq[gid] = packed;
}

// ---------------- Kernel B: ternary weight byte-masks + bias ----------------
__global__ void k_weights(const float* __restrict__ wgt,
                          const float* __restrict__ cbias,
                          const float* __restrict__ pmin,
                          uint2* __restrict__ wmask,
                          float* __restrict__ bias) {
    int o = threadIdx.x;                       // 64 threads, 1 block
    int sw = 0;
    for (int c = 0; c < NCH; ++c) {
        uint pm = 0, nm = 0;
#pragma unroll
        for (int k = 0; k < 4; ++k) {
            float v = wgt[o * CKK + c * 4 + k];
            if (v > 0.0f)      { pm |= 0xFFu << (8 * k); sw++; }
            else if (v < 0.0f) { nm |= 0xFFu << (8 * k); sw--; }
        }
        wmask[c * O_ + o] = make_uint2(pm, nm);
    }
    bias[o] = pmin[0] * (float)sw + cbias[o];
}

// ---------------- Kernel C: main fused gather-accumulate --------------------
__launch_bounds__(1024)
__global__ void k_main(const uint*  __restrict__ xq,
                       const uint2* __restrict__ wmask,
                       const float* __restrict__ bias,
                       const float* __restrict__ ptbl,
                       const float* __restrict__ pmin,
                       const float* __restrict__ pmax,
                       const int*   __restrict__ ridx,
                       float* __restrict__ out) {
    __shared__ _Float16 tbl[TROWS * TCOLS];   // 106,000 B : rows 8..60, fp16
    __shared__ uint2    s_w[NCH * O_];        //  18,432 B
    __shared__ uint     s_xq[16 * NCH];       //   2,304 B

    const int tid = threadIdx.x;
    for (int i = tid; i < TROWS * TCOLS; i += 1024)
        tbl[i] = (_Float16)ptbl[8 * TCOLS + i];
    for (int i = tid; i < NCH * O_; i += 1024)
        s_w[i] = wmask[i];

    const int o  = tid & 63;
    const int nl = tid >> 6;                  // 0..15 : n within tile
    const float sc = pmax[0] - pmin[0];
    const float bo = bias[o];

    for (int tile = blockIdx.x; tile < NTILES; tile += gridDim.x) {
        __syncthreads();                      // table/masks ready; prev tile done
        for (int i = tid; i < 16 * NCH; i += 1024)
            s_xq[i] = xq[tile * (16 * NCH) + i];
        __syncthreads();

        const int n = tile * 16 + nl;
        const int* rp = ridx + n * O_ + o;
        float sum = 0.0f;
#pragma unroll 4
        for (int c = 0; c < NCH; ++c) {
            uint  xv = s_xq[nl * NCH + c];        // broadcast within wave
            uint2 m  = s_w[c * O_ + o];
            uint yp = ((xv & m.x) * 0x01010101u) >> 24;   // dot4(Xq, w>0)
            uint ym = ((xv & m.y) * 0x01010101u) >> 24;   // dot4(Xq, w<0)
            int i0 = rp[(2 * c)     * PLANE];             // coalesced 256B/wave
            int i1 = rp[(2 * c + 1) * PLANE];
            if (yp >= 8) sum += (float)tbl[(yp - 8) * TCOLS + i0];
            if (ym >= 8) sum -= (float)tbl[(ym - 8) * TCOLS + i1];
        }
        // out[b][o][l],  b = n>>12, l = n & 4095
        out[(((n >> 12) * O_ + o) << 12) | (n & (L_ - 1))] = sum * sc + bo;
    }
}

extern "C" void kernel_launch(void* const* d_in, const int* in_sizes, int n_in,
                              void* d_out, int out_size, void* d_ws, size_t ws_size,
                              hipStream_t stream) {
    const float* x     = (const float*)d_in[0];
    const float* wgt   = (const float*)d_in[1];
    const float* cbias = (const float*)d_in[2];
    const float* pmin  = (const float*)d_in[3];
    const float* pmax  = (const float*)d_in[4];
    const float* ptbl  = (const float*)d_in[5];
    const int*   ridx  = (const int*)d_in[6];
    float* out = (float*)d_out;

    // workspace layout
    uint*  xq    = (uint*)d_ws;                                   // 1,179,648 B
    uint2* wmask = (uint2*)((char*)d_ws + 1179648);               //    18,432 B
    float* bias  = (float*)((char*)d_ws + 1179648 + 18432);       //       256 B

    k_quant  <<<(N_ * NCH) / 256, 256, 0, stream>>>(x, pmin, pmax, xq);
    k_weights<<<1, 64, 0, stream>>>(wgt, cbias, pmin, wmask, bias);
    k_main   <<<256, 1024, 0, stream>>>(xq, wmask, bias, ptbl, pmin, pmax, ridx, out);
}

// Round 2
// 54.804 us; speedup vs baseline: 1.1143x; 1.1143x over previous
//
#include <hip/hip_runtime.h>

typedef unsigned int uint;

// Problem constants (from setup_inputs)
#define B_     2
#define C_     16
#define H_     66
#define W_     66
#define O_     64
#define CKK    144
#define NCH    36          // CKK/4
#define DIM    64          // output spatial
#define L_     4096        // DIM*DIM
#define N_     8192        // B_*L_
#define PLANE  524288      // N_*O_  (stride between (c,s) planes of rand_idx)
#define NTILES 512         // N_/16
#define TROWS  53          // table rows 8..60
#define TCOLS  1000

// ---------------- Single fused persistent kernel ----------------------------
// Per block (1 block/CU, 256 blocks):
//   Phase 0 (once): fp16 prob_table rows 8..60 -> LDS; ternary weight byte
//                   masks -> LDS; per-o bias -> LDS.
//   Tile loop (2 tiles/block): quantize 16 patches from x -> s_xq (packed
//                   4-bit-in-byte, 4 channels per u32), then gather-accumulate
//                   against the coalesced rand_idx stream.
__launch_bounds__(1024)
__global__ void k_fused(const float* __restrict__ x,
                        const float* __restrict__ wgt,
                        const float* __restrict__ cbias,
                        const float* __restrict__ pmin,
                        const float* __restrict__ pmax,
                        const float* __restrict__ ptbl,
                        const int*   __restrict__ ridx,
                        float* __restrict__ out) {
    __shared__ _Float16 tbl[TROWS * TCOLS];   // 106,000 B
    __shared__ uint2    s_w[NCH * O_];        //  18,432 B
    __shared__ float    s_bias[O_];           //     256 B
    __shared__ uint     s_xq[16 * NCH];       //   2,304 B

    const int tid = threadIdx.x;

    // ---- Phase 0a: table -> LDS (fp16) ----
    for (int i = tid; i < TROWS * TCOLS; i += 1024)
        tbl[i] = (_Float16)ptbl[8 * TCOLS + i];

    // ---- Phase 0b: weight byte-masks -> LDS ----
    for (int p = tid; p < NCH * O_; p += 1024) {
        int c = p >> 6, oo = p & 63;
        uint pm = 0, nm = 0;
#pragma unroll
        for (int k = 0; k < 4; ++k) {
            float v = wgt[oo * CKK + c * 4 + k];
            if (v > 0.0f)      pm |= 0xFFu << (8 * k);
            else if (v < 0.0f) nm |= 0xFFu << (8 * k);
        }
        s_w[p] = make_uint2(pm, nm);
    }
    __syncthreads();

    // ---- Phase 0c: bias ----
    const float mn = pmin[0];
    const float sc = pmax[0] - mn;
    if (tid < O_) {
        int sw = 0;
        for (int c = 0; c < NCH; ++c) {
            uint2 m = s_w[c * O_ + tid];
            sw += (__popc(m.x) >> 3) - (__popc(m.y) >> 3);
        }
        s_bias[tid] = mn * (float)sw + cbias[tid];
    }
    __syncthreads();

    const int o  = tid & 63;
    const int nl = tid >> 6;                  // 0..15 : n within tile
    const float bo = s_bias[o];

    for (int tile = blockIdx.x; tile < NTILES; tile += gridDim.x) {
        __syncthreads();                      // prev tile's s_xq fully consumed

        // ---- quantize this tile's 16 patches (threads 0..575) ----
        if (tid < 16 * NCH) {
            int nl2 = tid / NCH;
            int c2  = tid - nl2 * NCH;
            int n2  = tile * 16 + nl2;
            int b2 = n2 >> 12, l2 = n2 & (L_ - 1);
            int h2 = l2 >> 6,  w2 = l2 & (DIM - 1);
            uint packed = 0;
#pragma unroll
            for (int k = 0; k < 4; ++k) {
                int j  = c2 * 4 + k;
                int ci = j / 9;
                int r  = j - ci * 9;
                int kh = r / 3;
                int kw = r - kh * 3;
                float v = x[((b2 * C_ + ci) * H_ + (h2 + kh)) * W_ + (w2 + kw)];
                float t = (v - mn) / sc * 15.0f;               // jax f32 op order
                float q = fminf(fmaxf(rintf(t), 0.0f), 15.0f); // round-half-even
                packed |= ((uint)q) << (8 * k);
            }
            s_xq[nl2 * NCH + c2] = packed;
        }
        __syncthreads();

        // ---- gather-accumulate over 36 chunk-planes x 2 signs ----
        const int n = tile * 16 + nl;
        const int* rp = ridx + n * O_ + o;
        float sum = 0.0f;
#pragma unroll 4
        for (int c = 0; c < NCH; ++c) {
            uint  xv = s_xq[nl * NCH + c];        // wave-broadcast
            uint2 m  = s_w[c * O_ + o];
            uint yp = ((xv & m.x) * 0x01010101u) >> 24;   // dot4(Xq, w>0)
            uint ym = ((xv & m.y) * 0x01010101u) >> 24;   // dot4(Xq, w<0)
            int i0 = rp[(2 * c)     * PLANE];             // coalesced 256B/wave
            int i1 = rp[(2 * c + 1) * PLANE];
            if (yp >= 8) sum += (float)tbl[(yp - 8) * TCOLS + i0];
            if (ym >= 8) sum -= (float)tbl[(ym - 8) * TCOLS + i1];
        }
        // out[b][o][l],  b = n>>12, l = n & 4095
        out[(((n >> 12) * O_ + o) << 12) | (n & (L_ - 1))] = sum * sc + bo;
    }
}

extern "C" void kernel_launch(void* const* d_in, const int* in_sizes, int n_in,
                              void* d_out, int out_size, void* d_ws, size_t ws_size,
                              hipStream_t stream) {
    const float* x     = (const float*)d_in[0];
    const float* wgt   = (const float*)d_in[1];
    const float* cbias = (const float*)d_in[2];
    const float* pmin  = (const float*)d_in[3];
    const float* pmax  = (const float*)d_in[4];
    const float* ptbl  = (const float*)d_in[5];
    const int*   ridx  = (const int*)d_in[6];
    float* out = (float*)d_out;

    k_fused<<<256, 1024, 0, stream>>>(x, wgt, cbias, pmin, pmax, ptbl, ridx, out);
}

// Round 3
// 34.955 us; speedup vs baseline: 1.7471x; 1.5678x over previous
//
#include <hip/hip_runtime.h>

typedef unsigned int uint;

// Problem constants (from setup_inputs)
#define B_     2
#define C_     16
#define H_     66
#define W_     66
#define O_     64
#define CKK    144
#define NCH    36          // CKK/4
#define DIM    64          // output spatial
#define L_     4096        // DIM*DIM
#define N_     8192        // B_*L_
#define PLANE  524288      // N_*O_  (stride between (c,s) planes of rand_idx)
#define TROWS  61          // table rows 0..60 (0..7 zeroed: sign(Q)==0 there)
#define TCOLS  1000

typedef _Float16 h4 __attribute__((ext_vector_type(4)));

// ---- prefetch group: 4 chunks x 2 signs x 2 streams = 16 coalesced loads ----
__device__ __forceinline__ void loadg(int (&buf)[16],
                                      const int* __restrict__ rp0,
                                      const int* __restrict__ rp1, int c0) {
#pragma unroll
    for (int j = 0; j < 4; ++j) {
        int c = c0 + j;
        buf[4 * j + 0] = rp0[(2 * c)     * PLANE];
        buf[4 * j + 1] = rp0[(2 * c + 1) * PLANE];
        buf[4 * j + 2] = rp1[(2 * c)     * PLANE];
        buf[4 * j + 3] = rp1[(2 * c + 1) * PLANE];
    }
}

// ---- consume one group: dot4 masks + 4 unconditional LDS gathers per j ----
__device__ __forceinline__ void procg(const int (&buf)[16],
                                      const uint* __restrict__ xq0,
                                      const uint* __restrict__ xq1,
                                      const uint2* __restrict__ sw,
                                      const _Float16* __restrict__ tbl,
                                      int c0, int o,
                                      float& sum0, float& sum1) {
#pragma unroll
    for (int j = 0; j < 4; ++j) {
        int c = c0 + j;
        uint xv0 = xq0[c];                      // wave-uniform LDS broadcast
        uint xv1 = xq1[c];
        uint2 m  = sw[c * O_ + o];
        uint yp0 = ((xv0 & m.x) * 0x01010101u) >> 24;
        uint ym0 = ((xv0 & m.y) * 0x01010101u) >> 24;
        uint yp1 = ((xv1 & m.x) * 0x01010101u) >> 24;
        uint ym1 = ((xv1 & m.y) * 0x01010101u) >> 24;
        sum0 += (float)tbl[yp0 * TCOLS + buf[4 * j + 0]];
        sum0 -= (float)tbl[ym0 * TCOLS + buf[4 * j + 1]];
        sum1 += (float)tbl[yp1 * TCOLS + buf[4 * j + 2]];
        sum1 -= (float)tbl[ym1 * TCOLS + buf[4 * j + 3]];
    }
}

__launch_bounds__(1024)
__global__ void k_fused(const float* __restrict__ x,
                        const float* __restrict__ wgt,
                        const float* __restrict__ cbias,
                        const float* __restrict__ pmin,
                        const float* __restrict__ pmax,
                        const float* __restrict__ ptbl,
                        const int*   __restrict__ ridx,
                        float* __restrict__ out) {
    __shared__ __align__(16) _Float16 tbl[TROWS * TCOLS]; // 122,000 B
    __shared__ uint2 s_w[NCH * O_];                       //  18,432 B
    __shared__ float s_bias[O_];                          //     256 B
    __shared__ uint  s_xq[2][16 * NCH];                   //   4,608 B

    const int tid = threadIdx.x;
    const float mn = pmin[0];
    const float sc = pmax[0] - mn;

    // ---- Phase 0a: zero rows 0..7 (16,000 B) as uint4 ----
    {
        uint4 z; z.x = z.y = z.z = z.w = 0u;
        uint4* zp = (uint4*)tbl;
        for (int p = tid; p < 1000; p += 1024) zp[p] = z;
    }
    // ---- Phase 0b: rows 8..60 -> fp16 LDS, float4-vectorized ----
    {
        const float4* src = (const float4*)(ptbl + 8 * TCOLS); // 16B aligned
        h4* dst = (h4*)(tbl + 8 * TCOLS);                      // 16B aligned
        for (int p = tid; p < (53 * TCOLS) / 4; p += 1024) {   // 13,250
            float4 v = src[p];
            h4 h = { (_Float16)v.x, (_Float16)v.y, (_Float16)v.z, (_Float16)v.w };
            dst[p] = h;
        }
    }
    // ---- Phase 0c: ternary weight byte-masks (float4 loads) ----
    for (int p = tid; p < NCH * O_; p += 1024) {               // 2,304
        int c = p >> 6, oo = p & 63;
        float4 v = *(const float4*)(wgt + oo * CKK + c * 4);   // 16B aligned
        uint pm = 0, nm = 0;
        if (v.x > 0.0f) pm |= 0x000000FFu; else if (v.x < 0.0f) nm |= 0x000000FFu;
        if (v.y > 0.0f) pm |= 0x0000FF00u; else if (v.y < 0.0f) nm |= 0x0000FF00u;
        if (v.z > 0.0f) pm |= 0x00FF0000u; else if (v.z < 0.0f) nm |= 0x00FF0000u;
        if (v.w > 0.0f) pm |= 0xFF000000u; else if (v.w < 0.0f) nm |= 0xFF000000u;
        s_w[p] = make_uint2(pm, nm);
    }
    // ---- Phase 0d: quantize both tiles' 32 patches into s_xq ----
    for (int i = tid; i < 2 * 16 * NCH; i += 1024) {           // 1,152
        int t  = i / (16 * NCH);
        int r  = i - t * (16 * NCH);
        int nl2 = r / NCH;
        int c2  = r - nl2 * NCH;
        int n2  = (blockIdx.x + t * 256) * 16 + nl2;
        int b2 = n2 >> 12, l2 = n2 & (L_ - 1);
        int h2 = l2 >> 6,  w2 = l2 & (DIM - 1);
        uint packed = 0;
#pragma unroll
        for (int k = 0; k < 4; ++k) {
            int j  = c2 * 4 + k;
            int ci = j / 9;
            int r2 = j - ci * 9;
            int kh = r2 / 3;
            int kw = r2 - kh * 3;
            float v = x[((b2 * C_ + ci) * H_ + (h2 + kh)) * W_ + (w2 + kw)];
            float t2 = (v - mn) / sc * 15.0f;                  // jax f32 op order
            float q = fminf(fmaxf(rintf(t2), 0.0f), 15.0f);
            packed |= ((uint)q) << (8 * k);
        }
        s_xq[t][r] = packed;
    }

    // ---- main: dual-stream, barrier-free, 2-deep prefetch pipeline ----
    const int o  = tid & 63;
    const int nl = tid >> 6;                   // 0..15
    const int n0 = blockIdx.x * 16 + nl;       // tile bid      (batch 0)
    const int n1 = n0 + 4096;                  // tile bid+256  (batch 1)
    const int* rp0 = ridx + n0 * O_ + o;
    const int* rp1 = ridx + n1 * O_ + o;

    int A[16], Bb[16];
    loadg(A,  rp0, rp1, 0);                    // in flight across the barrier
    loadg(Bb, rp0, rp1, 4);

    // bias from masks (needs s_w): compute after staging, before barrier use
    __syncthreads();
    if (tid < O_) {
        int sw2 = 0;
        for (int c = 0; c < NCH; ++c) {
            uint2 m = s_w[c * O_ + tid];
            sw2 += (__popc(m.x) >> 3) - (__popc(m.y) >> 3);
        }
        s_bias[tid] = mn * (float)sw2 + cbias[tid];
    }
    __syncthreads();

    const uint* xq0 = &s_xq[0][nl * NCH];
    const uint* xq1 = &s_xq[1][nl * NCH];
    const float bo  = s_bias[o];
    float sum0 = 0.0f, sum1 = 0.0f;

    procg(A,  xq0, xq1, s_w, tbl,  0, o, sum0, sum1); loadg(A,  rp0, rp1,  8);
    procg(Bb, xq0, xq1, s_w, tbl,  4, o, sum0, sum1); loadg(Bb, rp0, rp1, 12);
    procg(A,  xq0, xq1, s_w, tbl,  8, o, sum0, sum1); loadg(A,  rp0, rp1, 16);
    procg(Bb, xq0, xq1, s_w, tbl, 12, o, sum0, sum1); loadg(Bb, rp0, rp1, 20);
    procg(A,  xq0, xq1, s_w, tbl, 16, o, sum0, sum1); loadg(A,  rp0, rp1, 24);
    procg(Bb, xq0, xq1, s_w, tbl, 20, o, sum0, sum1); loadg(Bb, rp0, rp1, 28);
    procg(A,  xq0, xq1, s_w, tbl, 24, o, sum0, sum1); loadg(A,  rp0, rp1, 32);
    procg(Bb, xq0, xq1, s_w, tbl, 28, o, sum0, sum1);
    procg(A,  xq0, xq1, s_w, tbl, 32, o, sum0, sum1);

    // out[b][o][l]: n0 -> b=0,l=n0 ; n1 -> b=1,l=n1-4096
    out[o * L_ + n0]                       = sum0 * sc + bo;
    out[(O_ + o) * L_ + (n1 & (L_ - 1))]   = sum1 * sc + bo;
}

extern "C" void kernel_launch(void* const* d_in, const int* in_sizes, int n_in,
                              void* d_out, int out_size, void* d_ws, size_t ws_size,
                              hipStream_t stream) {
    const float* x     = (const float*)d_in[0];
    const float* wgt   = (const float*)d_in[1];
    const float* cbias = (const float*)d_in[2];
    const float* pmin  = (const float*)d_in[3];
    const float* pmax  = (const float*)d_in[4];
    const float* ptbl  = (const float*)d_in[5];
    const int*   ridx  = (const int*)d_in[6];
    float* out = (float*)d_out;

    k_fused<<<256, 1024, 0, stream>>>(x, wgt, cbias, pmin, pmax, ptbl, ridx, out);
}